// Round 11
// baseline (1707.989 us; speedup 1.0000x reference)
//
#include <hip/hip_runtime.h>
#include <cstdint>
#include <cstddef>

#define BB 16
#define NN 4096
#define SS 1024
#define KK 32
#define MROWS (BB*SS*KK)   // 524288 rows, one per (b,s,k)
#define EPSV 1e-5f
#define OUT_OFF1 (BB*3*SS) // 49152 floats: new_xyz chunk size

// ---------------- workspace layout (bytes), total ~37 MB ----------------
static constexpr size_t OFF_XYZT   = 0;                                    // float4[B*N]
static constexpr size_t OFF_NEWXYZ = OFF_XYZT   + (size_t)BB*NN*16;        // float4[B*S]
static constexpr size_t OFF_BALL   = OFF_NEWXYZ + (size_t)BB*SS*16;        // int[M]
static constexpr size_t OFF_STATS  = OFF_BALL   + (size_t)MROWS*4;         // float[512]
static constexpr size_t OFF_PROG   = OFF_STATS  + 2048;                    // int[16] progress
static constexpr size_t OFF_PT     = OFF_PROG   + 256;                     // float[B*N*64]
static constexpr size_t OFF_YMAX   = OFF_PT     + (size_t)BB*NN*64*4;      // float[B*S*128]
static constexpr size_t OFF_YMIN   = OFF_YMAX   + (size_t)BB*SS*128*4;     // float[B*S*128]

// Non-contractible fp32 ops: numpy computes mul+add (never FMA). hipcc ignores
// `#pragma clang fp contract(off)` for device code (proven rounds 1-8) — the
// _rn intrinsics are the only reliable way to match np's discrete decisions.
__device__ __forceinline__ float sq3(float x, float y, float z) {
  return __fadd_rn(__fadd_rn(__fmul_rn(x,x), __fmul_rn(y,y)), __fmul_rn(z,z));
}

// ---------------- mega kernel: FPS (0-15) + transposes (16-1039) + ball (1040-2063) ----------------
// FPS keys: u64 (nd_bits<<32 | 4095-n) viewed as double -> single v_max_f64 per
// compare. Sign bit always 0, exponent never all-ones (nd finite >= 0) => IEEE
// double order == u64 order == verified (value, smaller-index) tie-break.
// Ball blocks overlap under FPS via agent-scope progress counters (publish
// every 32 centroids; release/acquire atomics handle cross-XCD coherence).
__global__ __launch_bounds__(256) void fps_trans_ball(const float* __restrict__ xyz,
                                                      const float* __restrict__ pts,
                                                      float4* __restrict__ xyzt,
                                                      float* __restrict__ pt,
                                                      float4* __restrict__ newxyz,
                                                      int* __restrict__ prog,
                                                      int* __restrict__ ball,
                                                      float* __restrict__ out) {
  __shared__ float4 sxyz[NN];        // 64 KB (FPS blocks)
  __shared__ double red[2][4];
  __shared__ float tl[64*65];        // transpose staging
  int t = threadIdx.x;

  if (blockIdx.x >= 1040) {
    // ---------------- ball query (verified ballot form), overlapped ----------------
    int lane = t & 63, wv = t >> 6;
    int bs = (blockIdx.x - 1040)*4 + wv;
    int b = bs >> 10, s = bs & (SS-1);
    int need = s + 1;
    while (__hip_atomic_load(&prog[b], __ATOMIC_ACQUIRE, __HIP_MEMORY_SCOPE_AGENT) < need)
      __builtin_amdgcn_s_sleep(4);
    const float* xb = xyz + (size_t)b*3*NN;
    float4 c = newxyz[bs];
    float sumS = sq3(c.x, c.y, c.z);
    int count = 0;
    for (int ch = 0; ch < NN/64; ++ch) {
      int n = ch*64 + lane;
      float nx = xb[n], ny = xb[NN+n], nz = xb[2*NN+n];
      float sumN = sq3(nx, ny, nz);
      float dt   = __fadd_rn(__fadd_rn(__fmul_rn(c.x,nx), __fmul_rn(c.y,ny)), __fmul_rn(c.z,nz));
      float sqr  = __fsub_rn(__fadd_rn(sumS, sumN), __fmul_rn(2.0f, dt));
      bool isin = !(sqr > 0.04f);
      unsigned long long mask = __ballot(isin);
      int pos = count + (int)__popcll(mask & ((1ull << lane) - 1ull));
      if (isin && pos < KK) ball[(size_t)bs*KK + pos] = n;
      count += (int)__popcll(mask);
      if (count >= KK) break;
    }
    if (count < KK && lane >= count && lane < KK) ball[(size_t)bs*KK + lane] = NN-1;
    return;
  }

  if (blockIdx.x >= 16) {
    // ---------------- transpose work ----------------
    int k = blockIdx.x - 16;            // 1024 blocks: b = k>>6, n0 = (k&63)*64
    int b = k >> 6, n0 = (k & 63) * 64;
    int ln = t & 63, hi = t >> 6;
#pragma unroll
    for (int i = 0; i < 16; ++i) {
      int c = 4*i + hi;
      tl[c*65 + ln] = pts[((size_t)b*64 + c)*NN + n0 + ln];
    }
    if (t < 64) {
      int n = n0 + t;
      const float* xb = xyz + (size_t)b*3*NN;
      xyzt[(size_t)b*NN + n] = make_float4(xb[n], xb[NN+n], xb[2*NN+n], 0.f);
    }
    __syncthreads();
#pragma unroll
    for (int i = 0; i < 16; ++i) {
      int nn = hi + 4*i;
      pt[((size_t)b*NN + n0 + nn)*64 + ln] = tl[ln*65 + nn];
    }
    return;
  }

  // ---------------- FPS ----------------
  int b = blockIdx.x;
  int lane = t & 63, wv = t >> 6;
  const float* xb = xyz + (size_t)b*3*NN;
  float px[16], py[16], pz[16], dd[16];
  unsigned lokey[16];
#pragma unroll
  for (int j = 0; j < 16; ++j) {
    int n = t + 256*j;
    px[j] = xb[n]; py[j] = xb[NN+n]; pz[j] = xb[2*NN+n];
    sxyz[n] = make_float4(px[j], py[j], pz[j], 0.f);
    dd[j] = 1e10f;
    lokey[j] = (unsigned)(NN-1-n);
  }
  int f = 0;
  __syncthreads();
  for (int i = 0; i < SS; ++i) {
    float4 cc = sxyz[f];
    float cx = cc.x, cy = cc.y, cz = cc.z;
    if (t == 0) {
      newxyz[b*SS + i] = make_float4(cx, cy, cz, 0.f);
      out[(size_t)b*3*SS + i]        = cx;
      out[(size_t)b*3*SS + SS + i]   = cy;
      out[(size_t)b*3*SS + 2*SS + i] = cz;
      if ((i & 31) == 31)
        __hip_atomic_store(&prog[b], i+1, __ATOMIC_RELEASE, __HIP_MEMORY_SCOPE_AGENT);
    }
    if (i == SS-1) break;
    double key[16];
#pragma unroll
    for (int j = 0; j < 16; ++j) {
      float dx = __fsub_rn(px[j], cx);
      float dy = __fsub_rn(py[j], cy);
      float dz = __fsub_rn(pz[j], cz);
      float d  = sq3(dx, dy, dz);                // ((dx^2+dy^2)+dz^2), no FMA
      float nd = dd[j] < d ? dd[j] : d;
      dd[j] = nd;
      unsigned long long u = (((unsigned long long)__float_as_uint(nd)) << 32) | lokey[j];
      key[j] = __longlong_as_double((long long)u);
    }
    // in-thread tree max: 15 v_max_f64, 4 dependent levels
#pragma unroll
    for (int w = 8; w >= 1; w >>= 1)
#pragma unroll
      for (int q = 0; q < w; ++q)
        key[q] = fmax(key[q], key[q+w]);
    double bk = key[0];
#pragma unroll
    for (int m = 1; m < 64; m <<= 1)
      bk = fmax(bk, __shfl_xor(bk, m, 64));
    if (lane == 0) red[i&1][wv] = bk;
    __syncthreads();
    double best = fmax(fmax(red[i&1][0], red[i&1][1]), fmax(red[i&1][2], red[i&1][3]));
    unsigned long long ub = (unsigned long long)__double_as_longlong(best);
    f = (NN-1) - (int)(ub & 0xffffffffull);
  }
  if (t == 0)
    __hip_atomic_store(&prog[b], SS, __ATOMIC_RELEASE, __HIP_MEMORY_SCOPE_AGENT);
}

// ---------------- fused LDS-tiled recompute passes (verified) ----------------
template<int PASS>
__global__ __launch_bounds__(256) void fused_kernel(
    const float* __restrict__ pt, const float4* __restrict__ xyzt,
    const float4* __restrict__ newxyz, const int* __restrict__ ball,
    const float* __restrict__ W0g, const float* __restrict__ b0g,
    const float* __restrict__ W1g, const float* __restrict__ b1g,
    const float* __restrict__ W2g, const float* __restrict__ b2g,
    const float* __restrict__ stats,
    const float* __restrict__ g0, const float* __restrict__ be0,
    const float* __restrict__ g1, const float* __restrict__ be1,
    float* __restrict__ statsOut,
    float* __restrict__ ymax, float* __restrict__ ymin) {
  __shared__ float4 Xs4[128*17];     // 128 rows x 68 floats
  __shared__ float4 Wb4[68*16];      // up to 68 rows x 64 cols
  __shared__ float sc0[64], sh0[64], sc1[64], sh1[64];
  float* Wb = (float*)Wb4;

  int t = threadIdx.x;
  int tc = t & 15;
  int wv = t >> 6;
  int trs = (t >> 4) & 3;

  if constexpr (PASS >= 1) {
    if (t < 64) {
      float mean = stats[t] * (1.0f/MROWS);
      float var  = stats[64+t] * (1.0f/MROWS) - mean*mean;
      float s    = g0[t] / sqrtf(var + EPSV);
      sc0[t] = s; sh0[t] = be0[t] - mean*s;
    }
  }
  if constexpr (PASS == 2) {
    if (t < 64) {
      float mean = stats[128+t] * (1.0f/MROWS);
      float var  = stats[192+t] * (1.0f/MROWS) - mean*mean;
      float s    = g1[t] / sqrtf(var + EPSV);
      sc1[t] = s; sh1[t] = be1[t] - mean*s;
    }
  }

  float bj0[4], bj1[4], bj2[2][4];
#pragma unroll
  for (int j = 0; j < 4; ++j) {
    bj0[j] = b0g[tc*4 + j];
    if constexpr (PASS >= 1) bj1[j] = b1g[tc*4 + j];
    if constexpr (PASS == 2) { bj2[0][j] = b2g[tc*4 + j]; bj2[1][j] = b2g[64 + tc*4 + j]; }
  }

  float accS[4] = {0,0,0,0}, accQ[4] = {0,0,0,0};
  float accS2[2][4] = {{0,0,0,0},{0,0,0,0}};
  float accQ2[2][4] = {{0,0,0,0},{0,0,0,0}};

  auto loadW0 = [&]() {
    for (int idx = t; idx < 68*64; idx += 256) {
      int cc = idx >> 6, o = idx & 63;
      float v = 0.f;
      if (cc < 67) v = W0g[o*67 + (cc < 64 ? cc+3 : cc-64)];
      Wb[idx] = v;
    }
  };
  auto loadW64 = [&](const float* Wg) {
    for (int idx = t; idx < 64*64; idx += 256) {
      int cc = idx >> 6, o = idx & 63;
      Wb[idx] = Wg[o*64 + cc];
    }
  };
  auto conv = [&](int C4N, float (&acc)[8][4], const float (&bj)[4]) {
#pragma unroll
    for (int i = 0; i < 8; ++i)
#pragma unroll
      for (int j = 0; j < 4; ++j) acc[i][j] = bj[j];
    for (int c4 = 0; c4 < C4N; ++c4) {
      float4 a[8];
#pragma unroll
      for (int i = 0; i < 8; ++i) a[i] = Xs4[(32*wv + trs + 4*i)*17 + c4];
      float4 w0 = Wb4[(4*c4+0)*16 + tc];
      float4 w1 = Wb4[(4*c4+1)*16 + tc];
      float4 w2 = Wb4[(4*c4+2)*16 + tc];
      float4 w3 = Wb4[(4*c4+3)*16 + tc];
#pragma unroll
      for (int i = 0; i < 8; ++i) {
        acc[i][0] = fmaf(a[i].x, w0.x, acc[i][0]); acc[i][1] = fmaf(a[i].x, w0.y, acc[i][1]);
        acc[i][2] = fmaf(a[i].x, w0.z, acc[i][2]); acc[i][3] = fmaf(a[i].x, w0.w, acc[i][3]);
        acc[i][0] = fmaf(a[i].y, w1.x, acc[i][0]); acc[i][1] = fmaf(a[i].y, w1.y, acc[i][1]);
        acc[i][2] = fmaf(a[i].y, w1.z, acc[i][2]); acc[i][3] = fmaf(a[i].y, w1.w, acc[i][3]);
        acc[i][0] = fmaf(a[i].z, w2.x, acc[i][0]); acc[i][1] = fmaf(a[i].z, w2.y, acc[i][1]);
        acc[i][2] = fmaf(a[i].z, w2.z, acc[i][2]); acc[i][3] = fmaf(a[i].z, w2.w, acc[i][3]);
        acc[i][0] = fmaf(a[i].w, w3.x, acc[i][0]); acc[i][1] = fmaf(a[i].w, w3.y, acc[i][1]);
        acc[i][2] = fmaf(a[i].w, w3.z, acc[i][2]); acc[i][3] = fmaf(a[i].w, w3.w, acc[i][3]);
      }
    }
  };
  auto bnstore = [&](float (&acc)[8][4], const float* sc, const float* sh) {
    float s0 = sc[tc*4], s1 = sc[tc*4+1], s2 = sc[tc*4+2], s3 = sc[tc*4+3];
    float h0 = sh[tc*4], h1 = sh[tc*4+1], h2 = sh[tc*4+2], h3 = sh[tc*4+3];
#pragma unroll
    for (int i = 0; i < 8; ++i)
      Xs4[(32*wv + trs + 4*i)*17 + tc] = make_float4(
          fmaxf(0.f, fmaf(acc[i][0], s0, h0)), fmaxf(0.f, fmaf(acc[i][1], s1, h1)),
          fmaxf(0.f, fmaf(acc[i][2], s2, h2)), fmaxf(0.f, fmaf(acc[i][3], s3, h3)));
  };
  auto accum = [&](float (&acc)[8][4], float (&aS)[4], float (&aQ)[4]) {
#pragma unroll
    for (int i = 0; i < 8; ++i)
#pragma unroll
      for (int j = 0; j < 4; ++j) { float v = acc[i][j]; aS[j] += v; aQ[j] = fmaf(v, v, aQ[j]); }
  };
  auto maxmin = [&](float (&acc)[8][4], int h, int tile) {
    float vmx[4], vmn[4];
#pragma unroll
    for (int j = 0; j < 4; ++j) {
      float mx = acc[0][j], mn = acc[0][j];
#pragma unroll
      for (int i = 1; i < 8; ++i) { mx = fmaxf(mx, acc[i][j]); mn = fminf(mn, acc[i][j]); }
      vmx[j] = mx; vmn[j] = mn;
    }
#pragma unroll
    for (int m = 16; m <= 32; m <<= 1)
#pragma unroll
      for (int j = 0; j < 4; ++j) {
        vmx[j] = fmaxf(vmx[j], __shfl_xor(vmx[j], m, 64));
        vmn[j] = fminf(vmn[j], __shfl_xor(vmn[j], m, 64));
      }
    if ((t & 63) < 16) {
      size_t gg = (size_t)tile*4 + wv;
      ((float4*)(ymax + gg*128 + h*64 + tc*4))[0] = make_float4(vmx[0], vmx[1], vmx[2], vmx[3]);
      ((float4*)(ymin + gg*128 + h*64 + tc*4))[0] = make_float4(vmn[0], vmn[1], vmn[2], vmn[3]);
    }
  };

  for (int tile = blockIdx.x; tile < MROWS/128; tile += gridDim.x) {
    {
      int rr = t >> 1, p = t & 1;
      int r = tile*128 + rr;
      int n = ball[r];
      int bb2 = r >> 15;
      const float4* src = (const float4*)(pt + ((size_t)(bb2*NN + n))*64) + 8*p;
#pragma unroll
      for (int jj = 0; jj < 8; ++jj) Xs4[rr*17 + 8*p + jj] = src[jj];
      if (p == 0) {
        float4 pz = xyzt[bb2*NN + n];
        float4 q  = newxyz[r >> 5];
        float* X = (float*)Xs4;
        X[rr*68 + 64] = pz.x - q.x;
        X[rr*68 + 65] = pz.y - q.y;
        X[rr*68 + 66] = pz.z - q.z;
        X[rr*68 + 67] = 0.f;
      }
    }
    loadW0();
    __syncthreads();

    float acc[8][4];
    conv(17, acc, bj0);
    if constexpr (PASS == 0) {
      accum(acc, accS, accQ);
      __syncthreads();
      continue;
    }

    __syncthreads();
    bnstore(acc, sc0, sh0);
    loadW64(W1g);
    __syncthreads();

    float acc1[8][4];
    conv(16, acc1, bj1);
    if constexpr (PASS == 1) {
      accum(acc1, accS, accQ);
      __syncthreads();
      continue;
    }

    if constexpr (PASS == 2) {
      __syncthreads();
      bnstore(acc1, sc1, sh1);
      loadW64(W2g);
      __syncthreads();

      float acc2[8][4];
      conv(16, acc2, bj2[0]);
      accum(acc2, accS2[0], accQ2[0]);
      maxmin(acc2, 0, tile);
      __syncthreads();
      loadW64(W2g + 64*64);
      __syncthreads();

      conv(16, acc2, bj2[1]);
      accum(acc2, accS2[1], accQ2[1]);
      maxmin(acc2, 1, tile);
      __syncthreads();
    }
  }

  float* scratch = (float*)Xs4;
  constexpr int NSTAT = (PASS == 2) ? 256 : 128;
  if (t < NSTAT) scratch[t] = 0.f;
  __syncthreads();
  if constexpr (PASS <= 1) {
#pragma unroll
    for (int j = 0; j < 4; ++j) {
      atomicAdd(&scratch[tc*4 + j], accS[j]);
      atomicAdd(&scratch[64 + tc*4 + j], accQ[j]);
    }
  } else {
#pragma unroll
    for (int h = 0; h < 2; ++h)
#pragma unroll
      for (int j = 0; j < 4; ++j) {
        atomicAdd(&scratch[h*64 + tc*4 + j], accS2[h][j]);
        atomicAdd(&scratch[128 + h*64 + tc*4 + j], accQ2[h][j]);
      }
  }
  __syncthreads();
  if (t < NSTAT) atomicAdd(&statsOut[t], scratch[t]);
}

// ---------------- epilogue: BN2+relu on max/min-pooled conv2, transposed write ----------------
__global__ __launch_bounds__(256) void final_kernel(const float4* __restrict__ ymax4,
                                                    const float4* __restrict__ ymin4,
                                                    const float* __restrict__ stats2,
                                                    const float* __restrict__ g2,
                                                    const float* __restrict__ be2,
                                                    float* __restrict__ out) {
  __shared__ float sc3[128], sh3[128];
  __shared__ float tile[64*129];
  int t = threadIdx.x;
  if (t < 128) {
    float mean = stats2[t] * (1.0f/MROWS);
    float var  = stats2[128+t] * (1.0f/MROWS) - mean*mean;
    float sc   = g2[t] / sqrtf(var + EPSV);
    sc3[t] = sc; sh3[t] = be2[t] - mean*sc;
  }
  __syncthreads();
  int b = blockIdx.x, s0 = blockIdx.y*64;
#pragma unroll
  for (int pass = 0; pass < 8; ++pass) {
    int srow = pass*8 + (t >> 5);
    int o4 = (t & 31)*4;
    size_t base = (size_t)(b*SS + s0 + srow)*32 + (t & 31);
    float4 vx = ymax4[base], vn = ymin4[base];
#pragma unroll
    for (int e = 0; e < 4; ++e) {
      int o = o4 + e;
      float sc = sc3[o];
      float v = sc > 0.f ? ((const float*)&vx)[e] : ((const float*)&vn)[e];
      tile[srow*129 + o] = fmaxf(0.f, fmaf(v, sc, sh3[o]));
    }
  }
  __syncthreads();
  int s = t & 63;
  size_t obase = (size_t)OUT_OFF1 + (size_t)b*128*SS + s0 + s;
#pragma unroll
  for (int oi = 0; oi < 32; ++oi) {
    int o = (t >> 6) + 4*oi;
    out[obase + (size_t)o*SS] = tile[s*129 + o];
  }
}

extern "C" void kernel_launch(void* const* d_in, const int* in_sizes, int n_in,
                              void* d_out, int out_size, void* d_ws, size_t ws_size,
                              hipStream_t stream) {
  const float* xyz = (const float*)d_in[0];
  const float* pts = (const float*)d_in[1];
  const float* W0  = (const float*)d_in[2];
  const float* b0  = (const float*)d_in[3];
  const float* g0  = (const float*)d_in[4];
  const float* be0 = (const float*)d_in[5];
  const float* W1  = (const float*)d_in[6];
  const float* b1  = (const float*)d_in[7];
  const float* g1  = (const float*)d_in[8];
  const float* be1 = (const float*)d_in[9];
  const float* W2  = (const float*)d_in[10];
  const float* b2  = (const float*)d_in[11];
  const float* g2  = (const float*)d_in[12];
  const float* be2 = (const float*)d_in[13];
  float* out = (float*)d_out;
  char* ws = (char*)d_ws;

  float4* xyzt   = (float4*)(ws + OFF_XYZT);
  float4* newxyz = (float4*)(ws + OFF_NEWXYZ);
  int*    ball   = (int*)(ws + OFF_BALL);
  float*  stats  = (float*)(ws + OFF_STATS);
  int*    prog   = (int*)(ws + OFF_PROG);
  float*  pt     = (float*)(ws + OFF_PT);
  float*  ymax   = (float*)(ws + OFF_YMAX);
  float*  ymin   = (float*)(ws + OFF_YMIN);

  hipMemsetAsync(stats, 0, 2048 + 256, stream);   // stats + progress counters
  fps_trans_ball<<<16 + BB*(NN/64) + BB*SS/4, 256, 0, stream>>>(
      xyz, pts, xyzt, pt, newxyz, prog, ball, out);
  fused_kernel<0><<<1024, 256, 0, stream>>>(pt, xyzt, newxyz, ball, W0, b0, W1, b1, W2, b2,
      stats, g0, be0, g1, be1, stats, ymax, ymin);
  fused_kernel<1><<<1024, 256, 0, stream>>>(pt, xyzt, newxyz, ball, W0, b0, W1, b1, W2, b2,
      stats, g0, be0, g1, be1, stats + 128, ymax, ymin);
  fused_kernel<2><<<1024, 256, 0, stream>>>(pt, xyzt, newxyz, ball, W0, b0, W1, b1, W2, b2,
      stats, g0, be0, g1, be1, stats + 256, ymax, ymin);
  final_kernel<<<dim3(BB, SS/64), 256, 0, stream>>>((const float4*)ymax, (const float4*)ymin,
      stats + 256, g2, be2, out);
}

// Round 12
// 1537.888 us; speedup vs baseline: 1.1106x; 1.1106x over previous
//
#include <hip/hip_runtime.h>
#include <cstdint>
#include <cstddef>

#define BB 16
#define NN 4096
#define SS 1024
#define KK 32
#define MROWS (BB*SS*KK)   // 524288 rows, one per (b,s,k)
#define EPSV 1e-5f
#define OUT_OFF1 (BB*3*SS) // 49152 floats: new_xyz chunk size

// ---------------- workspace layout (bytes), total ~171 MB (proven safe r2) ----------------
static constexpr size_t OFF_XYZT   = 0;                                    // float4[B*N]
static constexpr size_t OFF_NEWXYZ = OFF_XYZT   + (size_t)BB*NN*16;        // float4[B*S]
static constexpr size_t OFF_BALL   = OFF_NEWXYZ + (size_t)BB*SS*16;        // int[M]
static constexpr size_t OFF_STATS  = OFF_BALL   + (size_t)MROWS*4;         // float[512]
static constexpr size_t OFF_PROG   = OFF_STATS  + 2048;                    // int[16] progress
static constexpr size_t OFF_PT     = OFF_PROG   + 256;                     // float[B*N*64]
static constexpr size_t OFF_Y      = OFF_PT     + (size_t)BB*NN*64*4;      // float[M*64] 134MB
static constexpr size_t OFF_YMAX   = OFF_Y      + (size_t)MROWS*64*4;      // float[B*S*128]
static constexpr size_t OFF_YMIN   = OFF_YMAX   + (size_t)BB*SS*128*4;     // float[B*S*128]

// Non-contractible fp32 ops: numpy computes mul+add (never FMA). hipcc ignores
// `#pragma clang fp contract(off)` for device code (proven rounds 1-8) — the
// _rn intrinsics are the only reliable way to match np's discrete decisions.
__device__ __forceinline__ float sq3(float x, float y, float z) {
  return __fadd_rn(__fadd_rn(__fmul_rn(x,x), __fmul_rn(y,y)), __fmul_rn(z,z));
}

// ---------------- mega kernel: FPS (0-15) + transposes (16-1039) + ball (1040-2063) ----
// FPS core is the round-10 u64-key form (833 us proven). Ball overlapped via
// agent-scope progress counters (publish every 32 centroids).
__global__ __launch_bounds__(256) void fps_trans_ball(const float* __restrict__ xyz,
                                                      const float* __restrict__ pts,
                                                      float4* __restrict__ xyzt,
                                                      float* __restrict__ pt,
                                                      float4* __restrict__ newxyz,
                                                      int* __restrict__ prog,
                                                      int* __restrict__ ball,
                                                      float* __restrict__ out) {
  __shared__ float sx[NN], sy[NN], sz[NN];       // 48 KB (FPS blocks)
  __shared__ unsigned long long red[2][4];
  __shared__ float tl[64*65];                    // transpose staging
  int t = threadIdx.x;

  if (blockIdx.x >= 1040) {
    // ---------------- ball query (verified ballot form), overlapped ----------------
    int lane = t & 63, wv = t >> 6;
    int bs = (blockIdx.x - 1040)*4 + wv;
    int b = bs >> 10, s = bs & (SS-1);
    int need = s + 1;
    while (__hip_atomic_load(&prog[b], __ATOMIC_ACQUIRE, __HIP_MEMORY_SCOPE_AGENT) < need)
      __builtin_amdgcn_s_sleep(4);
    const float* xb = xyz + (size_t)b*3*NN;
    float4 c = newxyz[bs];
    float sumS = sq3(c.x, c.y, c.z);
    int count = 0;
    for (int ch = 0; ch < NN/64; ++ch) {
      int n = ch*64 + lane;
      float nx = xb[n], ny = xb[NN+n], nz = xb[2*NN+n];
      float sumN = sq3(nx, ny, nz);
      float dt   = __fadd_rn(__fadd_rn(__fmul_rn(c.x,nx), __fmul_rn(c.y,ny)), __fmul_rn(c.z,nz));
      float sqr  = __fsub_rn(__fadd_rn(sumS, sumN), __fmul_rn(2.0f, dt));
      bool isin = !(sqr > 0.04f);
      unsigned long long mask = __ballot(isin);
      int pos = count + (int)__popcll(mask & ((1ull << lane) - 1ull));
      if (isin && pos < KK) ball[(size_t)bs*KK + pos] = n;
      count += (int)__popcll(mask);
      if (count >= KK) break;
    }
    if (count < KK && lane >= count && lane < KK) ball[(size_t)bs*KK + lane] = NN-1;
    return;
  }

  if (blockIdx.x >= 16) {
    // ---------------- transpose work ----------------
    int k = blockIdx.x - 16;            // 1024 blocks: b = k>>6, n0 = (k&63)*64
    int b = k >> 6, n0 = (k & 63) * 64;
    int ln = t & 63, hi = t >> 6;
#pragma unroll
    for (int i = 0; i < 16; ++i) {
      int c = 4*i + hi;
      tl[c*65 + ln] = pts[((size_t)b*64 + c)*NN + n0 + ln];
    }
    if (t < 64) {
      int n = n0 + t;
      const float* xb = xyz + (size_t)b*3*NN;
      xyzt[(size_t)b*NN + n] = make_float4(xb[n], xb[NN+n], xb[2*NN+n], 0.f);
    }
    __syncthreads();
#pragma unroll
    for (int i = 0; i < 16; ++i) {
      int nn = hi + 4*i;
      pt[((size_t)b*NN + n0 + nn)*64 + ln] = tl[ln*65 + nn];
    }
    return;
  }

  // ---------------- FPS (round-10 u64 form, bit-verified) ----------------
  int b = blockIdx.x;
  int lane = t & 63, wv = t >> 6;
  const float* xb = xyz + (size_t)b*3*NN;
  float px[16], py[16], pz[16], dd[16];
#pragma unroll
  for (int j = 0; j < 16; ++j) {
    int n = t + 256*j;
    px[j] = xb[n]; py[j] = xb[NN+n]; pz[j] = xb[2*NN+n];
    sx[n] = px[j]; sy[n] = py[j]; sz[n] = pz[j];
    dd[j] = 1e10f;
  }
  int f = 0;
  __syncthreads();
  for (int i = 0; i < SS; ++i) {
    float cx = sx[f], cy = sy[f], cz = sz[f];
    if (t == 0) {
      newxyz[b*SS + i] = make_float4(cx, cy, cz, 0.f);
      out[(size_t)b*3*SS + i]        = cx;
      out[(size_t)b*3*SS + SS + i]   = cy;
      out[(size_t)b*3*SS + 2*SS + i] = cz;
      if ((i & 31) == 31)
        __hip_atomic_store(&prog[b], i+1, __ATOMIC_RELEASE, __HIP_MEMORY_SCOPE_AGENT);
    }
    if (i == SS-1) break;
    unsigned long long key[16];
#pragma unroll
    for (int j = 0; j < 16; ++j) {
      float dx = __fsub_rn(px[j], cx);
      float dy = __fsub_rn(py[j], cy);
      float dz = __fsub_rn(pz[j], cz);
      float d  = sq3(dx, dy, dz);                // ((dx^2+dy^2)+dz^2), no FMA
      float nd = dd[j] < d ? dd[j] : d;
      dd[j] = nd;
      key[j] = (((unsigned long long)__float_as_uint(nd)) << 32)
             | (unsigned)(NN-1 - (t + 256*j));
    }
#pragma unroll
    for (int w = 8; w >= 1; w >>= 1)
#pragma unroll
      for (int q = 0; q < w; ++q)
        key[q] = key[q] > key[q+w] ? key[q] : key[q+w];
    unsigned long long bk = key[0];
#pragma unroll
    for (int m = 1; m < 64; m <<= 1) {
      unsigned long long ov = __shfl_xor(bk, m, 64);
      bk = ov > bk ? ov : bk;
    }
    if (lane == 0) red[i&1][wv] = bk;
    __syncthreads();
    unsigned long long best = red[i&1][0];
#pragma unroll
    for (int w = 1; w < 4; ++w) { unsigned long long v = red[i&1][w]; if (v > best) best = v; }
    f = (NN-1) - (int)(best & 0xffffffffull);
  }
  if (t == 0)
    __hip_atomic_store(&prog[b], SS, __ATOMIC_RELEASE, __HIP_MEMORY_SCOPE_AGENT);
}

// ---------------- store-y conv passes (round-2 verified structure) ----------------
// MODE 0: gather grouped features, conv 67->64, write y, stats0
// MODE 1: read y, apply BN0+relu, conv 64->64, write y in-place, stats1
// MODE 2: read y, apply BN1+relu, conv 64->128, stats2, per-(b,s) max&min over k
template<int MODE, int CO>
__global__ __launch_bounds__(256) void conv_kernel(
    const float* xin, const float4* __restrict__ xyzt, const float4* __restrict__ newxyz,
    const int* __restrict__ ball, const float* __restrict__ W, const float* __restrict__ bias,
    const float* __restrict__ statsPrev, const float* __restrict__ gPrev,
    const float* __restrict__ bePrev, float* yout, float* __restrict__ statsOut,
    float* __restrict__ ymax, float* __restrict__ ymin) {
  constexpr int NC = CO/16;
  constexpr int CR = (MODE == 0) ? 68 : 64;   // W rows in LDS (padded ci)
  constexpr int C4N = CR/4;
  __shared__ float4 Ws4[CR*CO/4];
  __shared__ float4 Xs4[128*17];              // 128 rows x 68 cols
  __shared__ float scIn[64], shIn[64];
  float* Ws = (float*)Ws4;

  int t = threadIdx.x;
  int tc = t & 15;
  int wv = t >> 6;
  int trs = (t >> 4) & 3;
  if constexpr (MODE >= 1) {
    if (t < 64) {
      float mean = statsPrev[t] * (1.0f/MROWS);
      float var  = statsPrev[64+t] * (1.0f/MROWS) - mean*mean;
      float inv  = 1.0f / sqrtf(var + EPSV);
      float sc   = gPrev[t] * inv;
      scIn[t] = sc; shIn[t] = bePrev[t] - mean*sc;
    }
  }
  for (int idx = t; idx < CR*CO; idx += 256) {
    int cc = idx / CO, o = idx % CO;
    float v = 0.f;
    if constexpr (MODE == 0) {
      if (cc < 67) v = W[o*67 + (cc < 64 ? cc+3 : cc-64)]; // cols: [points64, xyz3, 0]
    } else {
      if (cc < 64) v = W[o*64 + cc];
    }
    Ws[cc*CO + o] = v;
  }
  float bj[NC], accS[NC], accQ[NC];
#pragma unroll
  for (int j = 0; j < NC; ++j) { bj[j] = bias[tc*NC + j]; accS[j] = 0.f; accQ[j] = 0.f; }
  __syncthreads();

  for (int tile = blockIdx.x; tile < MROWS/128; tile += gridDim.x) {
    if constexpr (MODE == 0) {
      int rr = t >> 1, p = t & 1;
      int r = tile*128 + rr;
      int n = ball[r];
      int bb2 = r >> 15;
      const float4* src = (const float4*)(xin + ((size_t)(bb2*NN + n))*64) + 8*p;
#pragma unroll
      for (int jj = 0; jj < 8; ++jj) Xs4[rr*17 + 8*p + jj] = src[jj];
      if (p == 0) {
        float4 pz = xyzt[bb2*NN + n];
        float4 q  = newxyz[r >> 5];
        float* X = (float*)Xs4;
        X[rr*68 + 64] = pz.x - q.x;
        X[rr*68 + 65] = pz.y - q.y;
        X[rr*68 + 66] = pz.z - q.z;
        X[rr*68 + 67] = 0.f;
      }
    } else {
      const float4* src = (const float4*)(xin + (size_t)tile*128*64);
#pragma unroll
      for (int k = 0; k < 8; ++k) {
        int idx = t + 256*k;
        int row = idx >> 4, c4 = idx & 15;
        float4 v = src[idx];
        int c = 4*c4;
        v.x = fmaxf(0.f, fmaf(v.x, scIn[c+0], shIn[c+0]));
        v.y = fmaxf(0.f, fmaf(v.y, scIn[c+1], shIn[c+1]));
        v.z = fmaxf(0.f, fmaf(v.z, scIn[c+2], shIn[c+2]));
        v.w = fmaxf(0.f, fmaf(v.w, scIn[c+3], shIn[c+3]));
        Xs4[row*17 + c4] = v;
      }
    }
    __syncthreads();

    float acc[8][NC];
#pragma unroll
    for (int i = 0; i < 8; ++i)
#pragma unroll
      for (int j = 0; j < NC; ++j) acc[i][j] = bj[j];

    for (int c4 = 0; c4 < C4N; ++c4) {
      float4 a[8];
#pragma unroll
      for (int i = 0; i < 8; ++i) a[i] = Xs4[(32*wv + trs + 4*i)*17 + c4];
      float4 w[4][NC/4];
#pragma unroll
      for (int cc = 0; cc < 4; ++cc)
#pragma unroll
        for (int q = 0; q < NC/4; ++q)
          w[cc][q] = Ws4[(4*c4 + cc)*(CO/4) + tc*(NC/4) + q];
#pragma unroll
      for (int cc = 0; cc < 4; ++cc) {
#pragma unroll
        for (int i = 0; i < 8; ++i) {
          float av = (cc==0) ? a[i].x : (cc==1) ? a[i].y : (cc==2) ? a[i].z : a[i].w;
#pragma unroll
          for (int q = 0; q < NC/4; ++q) {
            acc[i][4*q+0] = fmaf(av, w[cc][q].x, acc[i][4*q+0]);
            acc[i][4*q+1] = fmaf(av, w[cc][q].y, acc[i][4*q+1]);
            acc[i][4*q+2] = fmaf(av, w[cc][q].z, acc[i][4*q+2]);
            acc[i][4*q+3] = fmaf(av, w[cc][q].w, acc[i][4*q+3]);
          }
        }
      }
    }

    if constexpr (MODE <= 1) {
#pragma unroll
      for (int i = 0; i < 8; ++i) {
        size_t rw = (size_t)tile*128 + 32*wv + trs + 4*i;
        float4 v = make_float4(acc[i][0], acc[i][1], acc[i][2], acc[i][3]);
        ((float4*)(yout + rw*64))[tc] = v;
      }
    }
#pragma unroll
    for (int i = 0; i < 8; ++i)
#pragma unroll
      for (int j = 0; j < NC; ++j) {
        float v = acc[i][j];
        accS[j] += v;
        accQ[j] = fmaf(v, v, accQ[j]);
      }

    if constexpr (MODE == 2) {
      float vmx[NC], vmn[NC];
#pragma unroll
      for (int j = 0; j < NC; ++j) {
        float mx = acc[0][j], mn = acc[0][j];
#pragma unroll
        for (int i = 1; i < 8; ++i) { mx = fmaxf(mx, acc[i][j]); mn = fminf(mn, acc[i][j]); }
        vmx[j] = mx; vmn[j] = mn;
      }
#pragma unroll
      for (int m = 16; m <= 32; m <<= 1)
#pragma unroll
        for (int j = 0; j < NC; ++j) {
          vmx[j] = fmaxf(vmx[j], __shfl_xor(vmx[j], m, 64));
          vmn[j] = fminf(vmn[j], __shfl_xor(vmn[j], m, 64));
        }
      if ((t & 63) < 16) {
        size_t gg = (size_t)tile*4 + wv;
        ((float4*)(ymax + gg*128 + 8*tc))[0] = make_float4(vmx[0], vmx[1], vmx[2], vmx[3]);
        ((float4*)(ymax + gg*128 + 8*tc))[1] = make_float4(vmx[4], vmx[5], vmx[6], vmx[7]);
        ((float4*)(ymin + gg*128 + 8*tc))[0] = make_float4(vmn[0], vmn[1], vmn[2], vmn[3]);
        ((float4*)(ymin + gg*128 + 8*tc))[1] = make_float4(vmn[4], vmn[5], vmn[6], vmn[7]);
      }
    }
    __syncthreads();
  }

  float* scratch = (float*)Xs4;
  if (t < 2*CO) scratch[t] = 0.f;
  __syncthreads();
#pragma unroll
  for (int j = 0; j < NC; ++j) {
    atomicAdd(&scratch[tc*NC + j], accS[j]);
    atomicAdd(&scratch[CO + tc*NC + j], accQ[j]);
  }
  __syncthreads();
  if (t < 2*CO) atomicAdd(&statsOut[t], scratch[t]);
}

// ---------------- epilogue: BN2+relu on max/min-pooled conv2, transposed write ----------------
__global__ __launch_bounds__(256) void final_kernel(const float4* __restrict__ ymax4,
                                                    const float4* __restrict__ ymin4,
                                                    const float* __restrict__ stats2,
                                                    const float* __restrict__ g2,
                                                    const float* __restrict__ be2,
                                                    float* __restrict__ out) {
  __shared__ float sc3[128], sh3[128];
  __shared__ float tile[64*129];
  int t = threadIdx.x;
  if (t < 128) {
    float mean = stats2[t] * (1.0f/MROWS);
    float var  = stats2[128+t] * (1.0f/MROWS) - mean*mean;
    float sc   = g2[t] / sqrtf(var + EPSV);
    sc3[t] = sc; sh3[t] = be2[t] - mean*sc;
  }
  __syncthreads();
  int b = blockIdx.x, s0 = blockIdx.y*64;
#pragma unroll
  for (int pass = 0; pass < 8; ++pass) {
    int srow = pass*8 + (t >> 5);
    int o4 = (t & 31)*4;
    size_t base = (size_t)(b*SS + s0 + srow)*32 + (t & 31);
    float4 vx = ymax4[base], vn = ymin4[base];
#pragma unroll
    for (int e = 0; e < 4; ++e) {
      int o = o4 + e;
      float sc = sc3[o];
      float v = sc > 0.f ? ((const float*)&vx)[e] : ((const float*)&vn)[e];
      tile[srow*129 + o] = fmaxf(0.f, fmaf(v, sc, sh3[o]));
    }
  }
  __syncthreads();
  int s = t & 63;
  size_t obase = (size_t)OUT_OFF1 + (size_t)b*128*SS + s0 + s;
#pragma unroll
  for (int oi = 0; oi < 32; ++oi) {
    int o = (t >> 6) + 4*oi;
    out[obase + (size_t)o*SS] = tile[s*129 + o];
  }
}

extern "C" void kernel_launch(void* const* d_in, const int* in_sizes, int n_in,
                              void* d_out, int out_size, void* d_ws, size_t ws_size,
                              hipStream_t stream) {
  const float* xyz = (const float*)d_in[0];
  const float* pts = (const float*)d_in[1];
  const float* W0  = (const float*)d_in[2];
  const float* b0  = (const float*)d_in[3];
  const float* g0  = (const float*)d_in[4];
  const float* be0 = (const float*)d_in[5];
  const float* W1  = (const float*)d_in[6];
  const float* b1  = (const float*)d_in[7];
  const float* g1  = (const float*)d_in[8];
  const float* be1 = (const float*)d_in[9];
  const float* W2  = (const float*)d_in[10];
  const float* b2  = (const float*)d_in[11];
  const float* g2  = (const float*)d_in[12];
  const float* be2 = (const float*)d_in[13];
  float* out = (float*)d_out;
  char* ws = (char*)d_ws;

  float4* xyzt   = (float4*)(ws + OFF_XYZT);
  float4* newxyz = (float4*)(ws + OFF_NEWXYZ);
  int*    ball   = (int*)(ws + OFF_BALL);
  float*  stats  = (float*)(ws + OFF_STATS);
  int*    prog   = (int*)(ws + OFF_PROG);
  float*  pt     = (float*)(ws + OFF_PT);
  float*  y      = (float*)(ws + OFF_Y);
  float*  ymax   = (float*)(ws + OFF_YMAX);
  float*  ymin   = (float*)(ws + OFF_YMIN);

  hipMemsetAsync(stats, 0, 2048 + 256, stream);   // stats + progress counters
  fps_trans_ball<<<16 + BB*(NN/64) + BB*SS/4, 256, 0, stream>>>(
      xyz, pts, xyzt, pt, newxyz, prog, ball, out);
  conv_kernel<0,64><<<1024, 256, 0, stream>>>(pt, xyzt, newxyz, ball, W0, b0,
      nullptr, nullptr, nullptr, y, stats, nullptr, nullptr);
  conv_kernel<1,64><<<1024, 256, 0, stream>>>(y, nullptr, nullptr, nullptr, W1, b1,
      stats, g0, be0, y, stats+128, nullptr, nullptr);
  conv_kernel<2,128><<<1024, 256, 0, stream>>>(y, nullptr, nullptr, nullptr, W2, b2,
      stats+128, g1, be1, nullptr, stats+256, ymax, ymin);
  final_kernel<<<dim3(BB, SS/64), 256, 0, stream>>>((const float4*)ymax, (const float4*)ymin,
      stats+256, g2, be2, out);
}